// Round 3
// baseline (185.835 us; speedup 1.0000x reference)
//
#include <hip/hip_runtime.h>

#define NS 256
#define NW 128
#define NH 768
#define NL 384          // TOPK*W keys
#define WH (NW*NH)      // 98304
#define OUTROWS 127

typedef __attribute__((ext_vector_type(8))) short short8;
typedef __attribute__((ext_vector_type(8))) unsigned short ushort8;
typedef __attribute__((ext_vector_type(8))) __bf16 bf16x8;
typedef __attribute__((ext_vector_type(4))) float f32x4;

#define XS_STRIDE 72                          // [384][72] bf16 rows (144B: phase spreads, conflict-free)
#define PS_STRIDE 392                         // [128][392] bf16 (784B rows)
#define SMEM_PS   (NL*XS_STRIDE*2)            // 55296
#define SMEM_RED  (SMEM_PS + 128*PS_STRIDE*2) // 155648
#define SMEM_TOTAL (SMEM_RED + 4096)          // 159744 <= 163840

__device__ __forceinline__ unsigned short bf16b(float f) {   // RNE software (cold paths only)
  union { float f; unsigned u; } x; x.f = f;
  return (unsigned short)((x.u + 0x7fffu + ((x.u >> 16) & 1u)) >> 16);
}
__device__ __forceinline__ float b2f(unsigned short h) {
  union { unsigned u; float f; } x; x.u = ((unsigned)h) << 16;
  return x.f;
}

// ---------------- top-3 nearest (stable, smallest-index ties) ----------------
__global__ __launch_bounds__(1024) void k_top3(const float* __restrict__ inp,
                                               int* __restrict__ idxw) {
  const int i = blockIdx.x, t = threadIdx.x;
  __shared__ float xi[772];                   // 4 segs of 193 (192 + 1 pad)
  __shared__ float dist[NS];
  __shared__ unsigned long long wkeys[16];
  for (int h = t; h < NH; h += 1024) xi[h + h / 192] = inp[(size_t)i * WH + h];
  __syncthreads();
  const int c = t >> 2, seg = t & 3;
  const float* __restrict__ row = inp + (size_t)c * WH + seg * 192;
  const float* xis = xi + seg * 193;
  float s = 0.f;
  #pragma unroll 4
  for (int h = 0; h < 192; h += 4) {
    float4 v = *(const float4*)(row + h);
    s += fabsf(xis[h]     - v.x) + fabsf(xis[h + 1] - v.y)
       + fabsf(xis[h + 2] - v.z) + fabsf(xis[h + 3] - v.w);
  }
  s += __shfl_xor(s, 1, 64);
  s += __shfl_xor(s, 2, 64);
  if (seg == 0) dist[c] = s;
  __syncthreads();
  for (int k = 0; k < 3; ++k) {
    float d = (t < NS) ? dist[t] : 3.4e38f;
    unsigned long long key = ((unsigned long long)__float_as_uint(d) << 32) | (unsigned)t;
    #pragma unroll
    for (int dd = 1; dd < 64; dd <<= 1) {
      unsigned long long o = __shfl_xor(key, dd, 64);
      key = (o < key) ? o : key;
    }
    if ((t & 63) == 0) wkeys[t >> 6] = key;
    __syncthreads();
    if (t == 0) {
      unsigned long long best = wkeys[0];
      for (int w = 1; w < 16; ++w) if (wkeys[w] < best) best = wkeys[w];
      int bj = (int)(best & 0xffffffffu);
      idxw[i * 3 + k] = bj;
      dist[bj] = 3.4e38f;
    }
    __syncthreads();
  }
}

// ---------------- PE table (bf16): pe[l][d] ----------------
__global__ __launch_bounds__(256) void k_pe(unsigned short* __restrict__ peb) {
  int gid = blockIdx.x * 256 + threadIdx.x;       // 384*768
  if (gid >= NL * NH) return;
  int l = gid / NH, d = gid - l * NH;
  const float c = -0.011992630687355995f;          // (float)(-log(1e4)/768)
  float dv = __expf((float)(d & ~1) * c);
  float ang = (float)l * dv;
  float v = (d & 1) ? cosf(ang) : sinf(ang);
  peb[gid] = bf16b(v);
}

// ---------------- fused attention: one block per s, 16 waves ----------------
__global__ __launch_bounds__(1024)
void k_attn(const float* __restrict__ inp, const unsigned short* __restrict__ peb,
            const int* __restrict__ idxw, float* __restrict__ out) {
  extern __shared__ char smem[];
  unsigned short* Xs = (unsigned short*)smem;              // QK: [384][72]; PV: VT [64][392] (swizzled)
  unsigned short* Ps = (unsigned short*)(smem + SMEM_PS);  // [128][392] normalized P (bf16)
  float* red = (float*)(smem + SMEM_RED);                  // [128][8]
  float* xch = (float*)(smem + SMEM_PS);                   // PV partial-O exchange (overlays Ps)

  const int s = blockIdx.x;
  const int tid = threadIdx.x;
  const int lane = tid & 63, wid = tid >> 6;
  const int lrow = lane & 15, lhi = lane >> 4;
  int idx3[3];
  idx3[0] = idxw[s * 3 + 0]; idx3[1] = idxw[s * 3 + 1]; idx3[2] = idxw[s * 3 + 2];

  const f32x4 fz = {0.f, 0.f, 0.f, 0.f};
  f32x4 acc[4][3];
  #pragma unroll
  for (int qs = 0; qs < 4; ++qs)
    #pragma unroll
    for (int kf = 0; kf < 3; ++kf) acc[qs][kf] = fz;

  const int qh = wid & 1, kq = wid >> 1;   // QK tiling: 64q x 48k per wave
  const int rl = tid >> 3, c8 = (tid & 7) * 8;

  // ============ QK^T: accumulate over 12 h-chunks of 64 ============
  for (int hc = 0; hc < 12; ++hc) {
    const int h0 = hc * 64;
    #pragma unroll
    for (int it = 0; it < 3; ++it) {
      const int r = rl + it * 128;
      const float* px = inp + (size_t)idx3[it] * WH + (size_t)rl * NH + h0 + c8;
      float4 a = *(const float4*)px;
      float4 b = *(const float4*)(px + 4);
      ushort8 pv = *(const ushort8*)&peb[r * NH + h0 + c8];
      bf16x8 o;
      o[0] = (__bf16)(a.x + b2f(pv[0])); o[1] = (__bf16)(a.y + b2f(pv[1]));
      o[2] = (__bf16)(a.z + b2f(pv[2])); o[3] = (__bf16)(a.w + b2f(pv[3]));
      o[4] = (__bf16)(b.x + b2f(pv[4])); o[5] = (__bf16)(b.y + b2f(pv[5]));
      o[6] = (__bf16)(b.z + b2f(pv[6])); o[7] = (__bf16)(b.w + b2f(pv[7]));
      *reinterpret_cast<bf16x8*>(&Xs[r * XS_STRIDE + c8]) = o;
    }
    __syncthreads();
    __builtin_amdgcn_s_setprio(1);
    #pragma unroll
    for (int ks = 0; ks < 64; ks += 32) {
      short8 a[4];
      #pragma unroll
      for (int qs = 0; qs < 4; ++qs)
        a[qs] = *reinterpret_cast<const short8*>(&Xs[(qh * 64 + qs * 16 + lrow) * XS_STRIDE + ks + lhi * 8]);
      #pragma unroll
      for (int kf = 0; kf < 3; ++kf) {
        short8 b = *reinterpret_cast<const short8*>(&Xs[(kq * 48 + kf * 16 + lrow) * XS_STRIDE + ks + lhi * 8]);
        #pragma unroll
        for (int qs = 0; qs < 4; ++qs)
          acc[qs][kf] = __builtin_amdgcn_mfma_f32_16x16x32_bf16(a[qs], b, acc[qs][kf], 0, 0, 0);
      }
    }
    __builtin_amdgcn_s_setprio(0);
    __syncthreads();
  }

  // ============ softmax (row partials across 8 kq-waves, red reused max->sum) ============
  const float scale = 0.03608439182435161f;  // 1/sqrt(768)
  float mx[4][4];
  #pragma unroll
  for (int qs = 0; qs < 4; ++qs)
    #pragma unroll
    for (int r = 0; r < 4; ++r) {
      float m = acc[qs][0][r];
      #pragma unroll
      for (int kf = 1; kf < 3; ++kf) m = fmaxf(m, acc[qs][kf][r]);
      #pragma unroll
      for (int d = 1; d < 16; d <<= 1) m = fmaxf(m, __shfl_xor(m, d, 64));
      mx[qs][r] = m;
    }
  if (lrow == 0) {
    #pragma unroll
    for (int qs = 0; qs < 4; ++qs)
      #pragma unroll
      for (int r = 0; r < 4; ++r)
        red[(qh * 64 + qs * 16 + lhi * 4 + r) * 8 + kq] = mx[qs][r];
  }
  __syncthreads();
  float sm[4][4];
  #pragma unroll
  for (int qs = 0; qs < 4; ++qs)
    #pragma unroll
    for (int r = 0; r < 4; ++r) {
      const int row = qh * 64 + qs * 16 + lhi * 4 + r;
      float4 m0 = *(const float4*)&red[row * 8];
      float4 m1 = *(const float4*)&red[row * 8 + 4];
      mx[qs][r] = fmaxf(fmaxf(fmaxf(m0.x, m0.y), fmaxf(m0.z, m0.w)),
                        fmaxf(fmaxf(m1.x, m1.y), fmaxf(m1.z, m1.w)));
      sm[qs][r] = 0.f;
    }
  #pragma unroll
  for (int qs = 0; qs < 4; ++qs)
    #pragma unroll
    for (int kf = 0; kf < 3; ++kf)
      #pragma unroll
      for (int r = 0; r < 4; ++r) {
        float p = __expf((acc[qs][kf][r] - mx[qs][r]) * scale);
        acc[qs][kf][r] = p;
        sm[qs][r] += p;
      }
  #pragma unroll
  for (int qs = 0; qs < 4; ++qs)
    #pragma unroll
    for (int r = 0; r < 4; ++r) {
      #pragma unroll
      for (int d = 1; d < 16; d <<= 1) sm[qs][r] += __shfl_xor(sm[qs][r], d, 64);
    }
  __syncthreads();    // all max-reads done; red reusable for sums
  if (lrow == 0) {
    #pragma unroll
    for (int qs = 0; qs < 4; ++qs)
      #pragma unroll
      for (int r = 0; r < 4; ++r)
        red[(qh * 64 + qs * 16 + lhi * 4 + r) * 8 + kq] = sm[qs][r];
  }
  __syncthreads();
  #pragma unroll
  for (int qs = 0; qs < 4; ++qs)
    #pragma unroll
    for (int r = 0; r < 4; ++r) {
      const int row = qh * 64 + qs * 16 + lhi * 4 + r;
      float4 s0 = *(const float4*)&red[row * 8];
      float4 s1 = *(const float4*)&red[row * 8 + 4];
      float t = (s0.x + s0.y) + (s0.z + s0.w) + (s1.x + s1.y) + (s1.z + s1.w);
      sm[qs][r] = 1.0f / t;
    }
  // write normalized P (bf16) -> Ps[q][m]
  #pragma unroll
  for (int qs = 0; qs < 4; ++qs)
    #pragma unroll
    for (int kf = 0; kf < 3; ++kf)
      #pragma unroll
      for (int r = 0; r < 4; ++r) {
        __bf16 pb = (__bf16)(acc[qs][kf][r] * sm[qs][r]);
        Ps[(qh * 64 + qs * 16 + lhi * 4 + r) * PS_STRIDE + kq * 48 + kf * 16 + lrow] =
            __builtin_bit_cast(unsigned short, pb);
      }
  __syncthreads();

  // ============ PV: O = P * V ============
  // wave = (ms, hh, qb): 32q x 32h x 192m per wave; ms pairs combine via xch.
  const int qb = wid & 3, hh = (wid >> 2) & 1, ms = wid >> 3;
  short8 pa[2][6];
  #pragma unroll
  for (int qs = 0; qs < 2; ++qs)
    #pragma unroll
    for (int mm = 0; mm < 6; ++mm)
      pa[qs][mm] = *reinterpret_cast<const short8*>(
          &Ps[(qb * 32 + qs * 16 + lrow) * PS_STRIDE + ms * 192 + mm * 32 + lhi * 8]);

  // VT[c][m] = x[m][h0+c], built via in-register 8x8 shuffle transpose, b128 stores.
  // Swizzle: byte ^= (j<<4) with j = c>>3 (both write and read sides).
  unsigned short* VT = Xs;                 // [64][392]
  const int g = lane & 7 ? 0 : 0;          // placeholder (g defined below per use)
  (void)g;
  const int gg = (lane >> 3) & 7;          // m-offset within wave's 8-row slab
  const int jj = lane & 7;                 // c8 group
  const int m0p_base = wid * 8;            // + it*128
  for (int t4 = 0; t4 < 12; ++t4) {
    const int h0 = t4 * 64;
    #pragma unroll
    for (int it = 0; it < 3; ++it) {
      const float* px = inp + (size_t)idx3[it] * WH + (size_t)rl * NH + h0 + c8;
      float4 a = *(const float4*)px;
      float4 b = *(const float4*)(px + 4);
      ushort8 pv = *(const ushort8*)&peb[(rl + it * 128) * NH + h0 + c8];
      float v[8];
      v[0] = a.x + b2f(pv[0]); v[1] = a.y + b2f(pv[1]);
      v[2] = a.z + b2f(pv[2]); v[3] = a.w + b2f(pv[3]);
      v[4] = b.x + b2f(pv[4]); v[5] = b.y + b2f(pv[5]);
      v[6] = b.z + b2f(pv[6]); v[7] = b.w + b2f(pv[7]);
      // 8x8 transpose across lanes {jj, jj+8, ..., jj+56}
      #pragma unroll
      for (int st = 0; st < 3; ++st) {
        const int k = 1 << st;
        #pragma unroll
        for (int p = 0; p < 4; ++p) {
          const int e0 = ((p & ~(k - 1)) << 1) | (p & (k - 1));
          const int e1 = e0 | k;
          const bool up = (gg & k) != 0;
          float xs = up ? v[e0] : v[e1];
          float y = __shfl_xor(xs, k * 8, 64);
          v[e0] = up ? y : v[e0];
          v[e1] = up ? v[e1] : y;
        }
      }
      // lane now holds column c = jj*8+gg, rows m0p..m0p+7
      const int c = jj * 8 + gg;
      const int m0p = m0p_base + it * 128;
      bf16x8 w;
      #pragma unroll
      for (int e = 0; e < 8; ++e) w[e] = (__bf16)v[e];
      *reinterpret_cast<bf16x8*>((char*)VT + (((c * PS_STRIDE + m0p) * 2) ^ (jj << 4))) = w;
    }
    __syncthreads();
    __builtin_amdgcn_s_setprio(1);
    f32x4 o00 = fz, o01 = fz, o10 = fz, o11 = fz;
    const int vr0 = hh * 32 + lrow, vr1 = vr0 + 16;
    const int sw0 = ((vr0 >> 3) & 7) << 4, sw1 = ((vr1 >> 3) & 7) << 4;
    #pragma unroll
    for (int mm = 0; mm < 6; ++mm) {
      const int moff = (ms * 192 + mm * 32 + lhi * 8) * 2;
      short8 b0 = *reinterpret_cast<const short8*>((const char*)VT + ((vr0 * PS_STRIDE * 2 + moff) ^ sw0));
      short8 b1 = *reinterpret_cast<const short8*>((const char*)VT + ((vr1 * PS_STRIDE * 2 + moff) ^ sw1));
      o00 = __builtin_amdgcn_mfma_f32_16x16x32_bf16(pa[0][mm], b0, o00, 0, 0, 0);
      o01 = __builtin_amdgcn_mfma_f32_16x16x32_bf16(pa[0][mm], b1, o01, 0, 0, 0);
      o10 = __builtin_amdgcn_mfma_f32_16x16x32_bf16(pa[1][mm], b0, o10, 0, 0, 0);
      o11 = __builtin_amdgcn_mfma_f32_16x16x32_bf16(pa[1][mm], b1, o11, 0, 0, 0);
    }
    __builtin_amdgcn_s_setprio(0);
    const int tb = qb * 2 + hh;
    if (ms == 1) {
      *(f32x4*)&xch[((0 * 8 + tb) * 64 + lane) * 4] = o00;
      *(f32x4*)&xch[((1 * 8 + tb) * 64 + lane) * 4] = o01;
      *(f32x4*)&xch[((2 * 8 + tb) * 64 + lane) * 4] = o10;
      *(f32x4*)&xch[((3 * 8 + tb) * 64 + lane) * 4] = o11;
    }
    __syncthreads();
    if (ms == 0) {
      o00 += *(const f32x4*)&xch[((0 * 8 + tb) * 64 + lane) * 4];
      o01 += *(const f32x4*)&xch[((1 * 8 + tb) * 64 + lane) * 4];
      o10 += *(const f32x4*)&xch[((2 * 8 + tb) * 64 + lane) * 4];
      o11 += *(const f32x4*)&xch[((3 * 8 + tb) * 64 + lane) * 4];
      float* ob = out + (size_t)s * (OUTROWS * NH) + h0 + hh * 32 + lrow;
      #pragma unroll
      for (int qs = 0; qs < 2; ++qs)
        #pragma unroll
        for (int hf = 0; hf < 2; ++hf) {
          f32x4 o = (qs == 0) ? (hf == 0 ? o00 : o01) : (hf == 0 ? o10 : o11);
          #pragma unroll
          for (int r = 0; r < 4; ++r) {
            const int q = qb * 32 + qs * 16 + lhi * 4 + r;
            if (q < OUTROWS) ob[(size_t)q * NH + hf * 16] = o[r];
          }
        }
    }
    // next stage writes VT (Xs region) only; ms0 xch reads complete before the
    // next xch write (which happens after the next post-stage barrier).
  }
}

// ---------------- launch ----------------
extern "C" void kernel_launch(void* const* d_in, const int* in_sizes, int n_in,
                              void* d_out, int out_size, void* d_ws, size_t ws_size,
                              hipStream_t stream) {
  (void)in_sizes; (void)n_in; (void)out_size; (void)ws_size;
  const float* inp = (const float*)d_in[0];
  float* out = (float*)d_out;
  char* ws = (char*)d_ws;

  unsigned short* peb = (unsigned short*)ws;                     // 589824 B
  int* idxw           = (int*)(ws + 589824);                     // 3072 B

  hipLaunchKernelGGL(k_top3, dim3(256), dim3(1024), 0, stream, inp, idxw);
  hipLaunchKernelGGL(k_pe, dim3(1152), dim3(256), 0, stream, peb);

  hipFuncSetAttribute((const void*)k_attn,
                      hipFuncAttributeMaxDynamicSharedMemorySize, SMEM_TOTAL);
  hipLaunchKernelGGL(k_attn, dim3(256), dim3(1024), SMEM_TOTAL, stream,
                     inp, peb, idxw, out);
}